// Round 20
// baseline (224.027 us; speedup 1.0000x reference)
//
#include <hip/hip_runtime.h>

// LIF neuron forward, v14: 2 independent chains per lane (C++ ILP, v10-style
// bit-pack — no SGPR/writelane hazard, no register spill).
// V = leak*V + I; spike = (V >= 1); V -= spike.
// current: [B=8, S=4096, D=1024] f32, membrane: [B, D] f32.
// Outputs concatenated: spikes [B,S,D] then mem_final [B,D], all f32.
//
// Evidence: v10 (75.2us) cadence 44cy/step = 4-op dep chain at ~7cy/op with
// no TLP on the consumer SIMD. v12 asm 2-chain hit VALU->SGPR->writelane
// waitstates (116us). v13 8-wave hit register spill (VGPR=52, 144us).
// v14: two chains interleaved in plain C++ (r7 proved 1.7x per-channel);
// masks stay in VGPRs (v10 bit-pack), channel-major in LDS. 256 blocks
// (CPB=32) so chip BW sustains the target cadence. v10 skeleton: CHUNK=256,
// NH=16, 2-slot ring, raw barriers, producer distance-1 vmcnt(0).
//
// Numerics (validated r5-r19, absmax 7.6e-6): forward spike == hard
// threshold exactly in fp32; fp contract(off) pins mul-then-add rounding;
// mem = f ? (v-1) : v bit-identical to v - spike.

#define LIF_B 8
#define LIF_S 4096
#define LIF_D 1024
#define CHUNK 256
#define NH    (LIF_S / CHUNK)   // 16
#define CPB   32                // channels per block

typedef __attribute__((address_space(3))) unsigned int lds_uint;
typedef const __attribute__((address_space(1))) unsigned int glb_uint;

// stage one 32KB chunk (256 rows x 32 ch) with 32 x 1KB global_load_lds.
__device__ __forceinline__ void stage_chunk32(const float* gwin, int tb,
                                              int prow, int pcol,
                                              float* slotbase) {
    #pragma unroll
    for (int f = 0; f < CHUNK / 8; ++f) {
        const float* src = gwin + (size_t)(tb + 8 * f + prow) * LIF_D + pcol;
        __builtin_amdgcn_global_load_lds(
            (glb_uint*)(const void*)src,
            (lds_uint*)(void*)(slotbase + (size_t)f * 256), 16, 0, 0);
    }
}

__global__ __launch_bounds__(256, 1) void lif_v14_kernel(
    const float* __restrict__ current,
    const float* __restrict__ membrane,
    float* __restrict__ spikes,
    float* __restrict__ mem_out)
{
    #pragma clang fp contract(off)

    __shared__ __align__(16) float in_ring[2][CHUNK][CPB];   // 64 KB
    __shared__ unsigned mask_lds[2][8][CPB];                 // 2 KB, channel-major

    const int wid  = threadIdx.x >> 6;   // 0=consumer 1=producer 2,3=writers
    const int lane = threadIdx.x & 63;
    const int blk  = blockIdx.x;         // 0..255
    const int bb   = blk >> 5;           // batch (1024/32 = 32 ch-blocks)
    const int ch0  = (blk & 31) * CPB;

    const float* gwin  = current + (size_t)bb * LIF_S * LIF_D + ch0;
    float*       sbase = spikes  + (size_t)bb * LIF_S * LIF_D + ch0;

    const int prow = lane >> 3;          // producer 8-row mapping
    const int pcol = (lane & 7) * 4;
    const int lx   = lane & 15;          // consumer channel-pair index

    float memA = 0.0f, memB = 0.0f;

    // ---- prologue: producer stages chunk 0; consumer loads membrane ----
    if (wid == 1) {
        stage_chunk32(gwin, 0, prow, pcol, &in_ring[0][0][0]);
        asm volatile("s_waitcnt vmcnt(0)" ::: "memory");
    } else if (wid == 0) {
        const float2 mm = *(const float2*)&membrane[bb * LIF_D + ch0 + 2 * lx];
        memA = mm.x; memB = mm.y;
    }
    __builtin_amdgcn_s_barrier();
    asm volatile("" ::: "memory");

    for (int h = 0; h < NH; ++h) {
        if (wid == 0) {
            // ---- consumer: 256 steps, 2 chains/lane, v10 bit-pack ----
            const float2* ib2 = (const float2*)&in_ring[h & 1][0][0];
            unsigned mA[8], mB[8];
            #pragma unroll
            for (int j = 0; j < 8; ++j) { mA[j] = 0u; mB[j] = 0u; }

            float2 A[16], Bv[16];
            #pragma unroll
            for (int j = 0; j < 16; ++j) A[j]  = ib2[j * 16 + lx];
            #pragma unroll
            for (int j = 0; j < 16; ++j) Bv[j] = ib2[(16 + j) * 16 + lx];

            #pragma unroll
            for (int b = 0; b < 16; ++b) {
                const int wd = b >> 1;          // mask word (static)
                const int sh = (b & 1) * 16;    // bit base (static)
                #pragma unroll
                for (int j = 0; j < 16; ++j) {
                    const float2 c = ((b & 1) == 0) ? A[j] : Bv[j];  // static
                    const float vA = 0.9f * memA + c.x;   // mul-then-add
                    const float vB = 0.9f * memB + c.y;
                    const float wA = vA - 1.0f;           // off chain
                    const float wB = vB - 1.0f;
                    const bool  fA = (vA >= 1.0f);
                    const bool  fB = (vB >= 1.0f);
                    mA[wd] |= fA ? (1u << (sh + j)) : 0u;
                    mB[wd] |= fB ? (1u << (sh + j)) : 0u;
                    memA = fA ? wA : vA;                  // soft reset
                    memB = fB ? wB : vB;
                }
                if (b + 2 < 16) {                         // prefetch batch b+2
                    #pragma unroll
                    for (int j = 0; j < 16; ++j) {
                        if ((b & 1) == 0) A[j]  = ib2[((b + 2) * 16 + j) * 16 + lx];
                        else              Bv[j] = ib2[((b + 2) * 16 + j) * 16 + lx];
                    }
                }
            }

            if (lane < 16) {
                #pragma unroll
                for (int j = 0; j < 8; ++j)
                    *(uint2*)&mask_lds[h & 1][j][2 * lx]
                        = make_uint2(mA[j], mB[j]);   // ch 2lx, 2lx+1
            }
            asm volatile("s_waitcnt lgkmcnt(0)" ::: "memory");
        } else if (wid == 1) {
            // ---- producer: stage chunk h+1 into the other slot ----
            if (h + 1 < NH) {
                stage_chunk32(gwin, (h + 1) * CHUNK, prow, pcol,
                              &in_ring[(h + 1) & 1][0][0]);
                asm volatile("s_waitcnt vmcnt(0)" ::: "memory");
            }
        } else {
            // ---- writers: expand channel-major masks of phase h-1 ----
            if (h >= 1) {
                const int ph = (h - 1) & 1;
                const int tb = (h - 1) * CHUNK;
                const int rbase = (wid == 3) ? 128 : 0;
                const int chb   = lane & 31;          // channel = word index
                const int rhalf = lane >> 5;          // 0/1
                #pragma unroll 8
                for (int k = 0; k < 64; ++k) {
                    const int row = rbase + 2 * k + rhalf;          // local row
                    const unsigned m = mask_lds[ph][row >> 5][chb];
                    const float sv = (float)((m >> (row & 31)) & 1u);
                    sbase[(size_t)(tb + row) * LIF_D + chb] = sv;
                }
                asm volatile("s_waitcnt lgkmcnt(0)" ::: "memory");
            }
        }
        __builtin_amdgcn_s_barrier();
        asm volatile("" ::: "memory");
    }

    // ---- epilogue: flush masks of phase NH-1; store final membrane ----
    if (wid >= 2) {
        const int ph = (NH - 1) & 1;
        const int tb = (NH - 1) * CHUNK;
        const int rbase = (wid == 3) ? 128 : 0;
        const int chb   = lane & 31;
        const int rhalf = lane >> 5;
        #pragma unroll 8
        for (int k = 0; k < 64; ++k) {
            const int row = rbase + 2 * k + rhalf;
            const unsigned m = mask_lds[ph][row >> 5][chb];
            const float sv = (float)((m >> (row & 31)) & 1u);
            sbase[(size_t)(tb + row) * LIF_D + chb] = sv;
        }
    } else if (wid == 0 && lane < 16) {
        *(float2*)&mem_out[bb * LIF_D + ch0 + 2 * lane]
            = make_float2(memA, memB);
    }
}

extern "C" void kernel_launch(void* const* d_in, const int* in_sizes, int n_in,
                              void* d_out, int out_size, void* d_ws, size_t ws_size,
                              hipStream_t stream) {
    const float* current  = (const float*)d_in[0];   // [8, 4096, 1024]
    const float* membrane = (const float*)d_in[1];   // [8, 1024]

    float* spikes  = (float*)d_out;                                 // [8,4096,1024]
    float* mem_out = (float*)d_out + (size_t)LIF_B * LIF_S * LIF_D; // [8,1024]

    dim3 block(256);                   // w0 consumer, w1 producer, w2-3 writers
    dim3 grid(LIF_B * LIF_D / CPB);    // 256 blocks (32 channels each)

    hipLaunchKernelGGL(lif_v14_kernel, grid, block, 0, stream,
                       current, membrane, spikes, mem_out);
}

// Round 21
// 145.124 us; speedup vs baseline: 1.5437x; 1.5437x over previous
//
#include <hip/hip_runtime.h>

// LIF neuron forward, v15: v13's same-SIMD dual consumers, spill-fixed.
// V = leak*V + I; spike = (V >= 1); V -= spike.
// current: [B=8, S=4096, D=1024] f32, membrane: [B, D] f32.
// Outputs concatenated: spikes [B,S,D] then mem_final [B,D], all f32.
//
// v13 (144us) died of register spill: consumer needed ~55 live VGPRs,
// launch_bounds(512,1) made the allocator grant 52 -> scratch in the hot
// loop. v15 fixes BOTH sides: __launch_bounds__(512,2) budgets for the
// real occupancy (2 waves/SIMD, <=128 VGPR/wave), and the consumer drops
// to batch-of-8 double-buffer (A[8]+Bv[8]+m[8] ~= 40 VGPR). Waves 0,4
// (both SIMD0 by i%4) round-robin issue -> each fills the other's ~7cy
// dependent-VALU gaps -> target cadence ~28-30cy vs 43 solo.
// Skeleton = v13: 256 blocks, CPB=32, CHUNK=256, NH=16, 2-slot ring,
// w1/w5 producers (half chunk each), w2/w3/w6/w7 writers, raw barriers.
//
// Numerics (validated r5-r20, absmax 7.6e-6): forward spike == hard
// threshold exactly in fp32; fp contract(off) pins mul-then-add rounding;
// mem = f ? (v-1) : v bit-identical to v - spike.

#define LIF_B 8
#define LIF_S 4096
#define LIF_D 1024
#define CHUNK 256
#define NH    (LIF_S / CHUNK)   // 16
#define CPB   32                // channels per block

typedef __attribute__((address_space(3))) unsigned int lds_uint;
typedef const __attribute__((address_space(1))) unsigned int glb_uint;

__global__ __launch_bounds__(512, 2) void lif_v15_kernel(
    const float* __restrict__ current,
    const float* __restrict__ membrane,
    float* __restrict__ spikes,
    float* __restrict__ mem_out)
{
    #pragma clang fp contract(off)

    __shared__ __align__(16) float in_ring[2][CHUNK][CPB];   // 64 KB
    __shared__ unsigned mask_lds[2][8][CPB];                 // 2 KB spike bits

    const int wid  = threadIdx.x >> 6;   // 0,4=consumers 1,5=producers rest=writers
    const int lane = threadIdx.x & 63;
    const int blk  = blockIdx.x;         // 0..255
    const int bb   = blk >> 5;           // batch (1024/32 = 32 ch-blocks)
    const int ch0  = (blk & 31) * CPB;

    const float* gwin  = current + (size_t)bb * LIF_S * LIF_D + ch0;
    float*       sbase = spikes  + (size_t)bb * LIF_S * LIF_D + ch0;

    const int prow = lane >> 3;          // producer 8-row mapping
    const int pcol = (lane & 7) * 4;
    const int lx   = lane & 15;

    const bool is_cons = (wid == 0) || (wid == 4);
    const bool is_prod = (wid == 1) || (wid == 5);
    const int  co      = (wid == 4) ? 16 : 0;          // consumer ch offset
    const int  phalf   = (wid == 5) ? 1 : 0;           // producer row half
    const int  wi      = (wid == 2) ? 0 : (wid == 3) ? 1 : (wid == 6) ? 2 : 3;

    float mem = 0.0f;

    // ---- prologue: producers stage chunk 0; consumers load membrane ----
    if (is_prod) {
        #pragma unroll
        for (int f = 0; f < 16; ++f) {
            const float* src = gwin
                + (size_t)(phalf * 128 + 8 * f + prow) * LIF_D + pcol;
            __builtin_amdgcn_global_load_lds(
                (glb_uint*)(const void*)src,
                (lds_uint*)(void*)(&in_ring[0][0][0]
                                   + (size_t)(phalf * 16 + f) * 256), 16, 0, 0);
        }
        asm volatile("s_waitcnt vmcnt(0)" ::: "memory");
    } else if (is_cons) {
        mem = membrane[bb * LIF_D + ch0 + co + lx];
    }
    __builtin_amdgcn_s_barrier();
    asm volatile("" ::: "memory");

    for (int h = 0; h < NH; ++h) {
        if (is_cons) {
            // ---- consumer: 256 steps = 32 static batches of 8 ----
            const float* ib = &in_ring[h & 1][0][co + lx];
            unsigned m[8];
            #pragma unroll
            for (int j = 0; j < 8; ++j) m[j] = 0u;

            float A[8], Bv[8];
            #pragma unroll
            for (int j = 0; j < 8; ++j) A[j]  = ib[j * CPB];
            #pragma unroll
            for (int j = 0; j < 8; ++j) Bv[j] = ib[(8 + j) * CPB];

            #pragma unroll
            for (int b = 0; b < 32; ++b) {
                const int wd = b >> 2;          // mask word (static)
                const int sh = (b & 3) * 8;     // bit base (static)
                #pragma unroll
                for (int j = 0; j < 8; ++j) {
                    const float c = ((b & 1) == 0) ? A[j] : Bv[j];  // static
                    const float v = 0.9f * mem + c;   // mul-then-add
                    const float w = v - 1.0f;         // off chain
                    const bool  f = (v >= 1.0f);
                    m[wd] |= f ? (1u << (sh + j)) : 0u;
                    mem = f ? w : v;                  // soft reset
                }
                if (b + 2 < 32) {                     // prefetch batch b+2
                    #pragma unroll
                    for (int j = 0; j < 8; ++j) {
                        if ((b & 1) == 0) A[j]  = ib[((b + 2) * 8 + j) * CPB];
                        else              Bv[j] = ib[((b + 2) * 8 + j) * CPB];
                    }
                }
            }

            if (lane < 16) {
                #pragma unroll
                for (int j = 0; j < 8; ++j)
                    mask_lds[h & 1][j][co + lane] = m[j];
            }
            asm volatile("s_waitcnt lgkmcnt(0)" ::: "memory");
        } else if (is_prod) {
            // ---- producers: stage chunk h+1 (half each) ----
            if (h + 1 < NH) {
                const int tb = (h + 1) * CHUNK;
                #pragma unroll
                for (int f = 0; f < 16; ++f) {
                    const float* src = gwin
                        + (size_t)(tb + phalf * 128 + 8 * f + prow) * LIF_D + pcol;
                    __builtin_amdgcn_global_load_lds(
                        (glb_uint*)(const void*)src,
                        (lds_uint*)(void*)(&in_ring[(h + 1) & 1][0][0]
                                           + (size_t)(phalf * 16 + f) * 256),
                        16, 0, 0);
                }
                asm volatile("s_waitcnt vmcnt(0)" ::: "memory");
            }
        } else {
            // ---- writers: expand masks of phase h-1 -> float4 stores ----
            if (h >= 1) {
                const int ph = (h - 1) & 1;
                const int tb = (h - 1) * CHUNK;
                const int whalf = lane >> 5;          // 0/1
                const int wIdx  = 2 * wi + whalf;     // mask word 0..7
                const int c4    = lane & 7;           // float4 col group
                const int rsub  = (lane >> 3) & 3;    // row sub-group
                const int rb    = wi * 64 + whalf * 32;
                unsigned M[4];
                #pragma unroll
                for (int c = 0; c < 4; ++c)
                    M[c] = mask_lds[ph][wIdx][4 * c4 + c];
                #pragma unroll
                for (int k = 0; k < 8; ++k) {
                    const int rloc = rsub * 8 + k;    // row&31
                    const int row  = rb + rloc;
                    float4 vv;
                    vv.x = (float)((M[0] >> rloc) & 1u);
                    vv.y = (float)((M[1] >> rloc) & 1u);
                    vv.z = (float)((M[2] >> rloc) & 1u);
                    vv.w = (float)((M[3] >> rloc) & 1u);
                    *(float4*)(sbase + (size_t)(tb + row) * LIF_D + 4 * c4) = vv;
                }
                asm volatile("s_waitcnt lgkmcnt(0)" ::: "memory");
            }
        }
        __builtin_amdgcn_s_barrier();
        asm volatile("" ::: "memory");
    }

    // ---- epilogue: flush masks of phase NH-1; store final membrane ----
    if (!is_cons && !is_prod) {
        const int ph = (NH - 1) & 1;
        const int tb = (NH - 1) * CHUNK;
        const int whalf = lane >> 5;
        const int wIdx  = 2 * wi + whalf;
        const int c4    = lane & 7;
        const int rsub  = (lane >> 3) & 3;
        const int rb    = wi * 64 + whalf * 32;
        unsigned M[4];
        #pragma unroll
        for (int c = 0; c < 4; ++c)
            M[c] = mask_lds[ph][wIdx][4 * c4 + c];
        #pragma unroll
        for (int k = 0; k < 8; ++k) {
            const int rloc = rsub * 8 + k;
            const int row  = rb + rloc;
            float4 vv;
            vv.x = (float)((M[0] >> rloc) & 1u);
            vv.y = (float)((M[1] >> rloc) & 1u);
            vv.z = (float)((M[2] >> rloc) & 1u);
            vv.w = (float)((M[3] >> rloc) & 1u);
            *(float4*)(sbase + (size_t)(tb + row) * LIF_D + 4 * c4) = vv;
        }
    } else if (is_cons && lane < 16) {
        mem_out[bb * LIF_D + ch0 + co + lane] = mem;
    }
}

extern "C" void kernel_launch(void* const* d_in, const int* in_sizes, int n_in,
                              void* d_out, int out_size, void* d_ws, size_t ws_size,
                              hipStream_t stream) {
    const float* current  = (const float*)d_in[0];   // [8, 4096, 1024]
    const float* membrane = (const float*)d_in[1];   // [8, 1024]

    float* spikes  = (float*)d_out;                                 // [8,4096,1024]
    float* mem_out = (float*)d_out + (size_t)LIF_B * LIF_S * LIF_D; // [8,1024]

    dim3 block(512);                   // 8 waves: w0/w4 consumers (same SIMD),
    dim3 grid(LIF_B * LIF_D / CPB);    //   w1/w5 producers, rest writers

    hipLaunchKernelGGL(lif_v15_kernel, grid, block, 0, stream,
                       current, membrane, spikes, mem_out);
}

// Round 22
// 124.707 us; speedup vs baseline: 1.7964x; 1.1637x over previous
//
#include <hip/hip_runtime.h>

// LIF neuron forward, v16: 2 INDEPENDENT blocks per CU (CPB=16, 512 blocks).
// V = leak*V + I; spike = (V >= 1); V -= spike.
// current: [B=8, S=4096, D=1024] f32, membrane: [B, D] f32.
// Outputs concatenated: spikes [B,S,D] then mem_final [B,D], all f32.
//
// Evidence r5-r21: consumer cadence 43-44cy/step invariant across 7
// structural variants; same-BLOCK dual consumers (v13/v15) cost 2x
// (8-wave barrier coupling / SIMD placement), asm variants hit hazards,
// fat-register variants spill. v16 = v11's proven 4-wave structure with
// CPB=16 -> LDS 34KB -> 512 blocks = 2 independent blocks/CU. Two
// consumer waves per CU with ZERO shared barriers; if co-placed on a
// SIMD, round-robin issue fills the ~7cy dependent-VALU gaps for free.
// Downside bounded: v5->v6 proved cadence invariant to CPB shrink.
//
// Numerics (validated r5-r21, absmax 7.6e-6): forward spike == hard
// threshold exactly in fp32; fp contract(off) pins mul-then-add rounding;
// mem = f ? (v-1) : v bit-identical to v - spike.

#define LIF_B 8
#define LIF_S 4096
#define LIF_D 1024
#define CHUNK 256
#define NH    (LIF_S / CHUNK)   // 16
#define CPB   16                // channels per block

typedef __attribute__((address_space(3))) unsigned int lds_uint;
typedef const __attribute__((address_space(1))) unsigned int glb_uint;

// stage one 16KB chunk (256 rows x 16 ch) with 16 x 1KB global_load_lds.
// lane L -> row (L>>2) within a 16-row group, float col (L&3)*4.
__device__ __forceinline__ void stage_chunk16(const float* gwin, int tb,
                                              int prow, int pcol,
                                              float* slotbase) {
    #pragma unroll
    for (int f = 0; f < CHUNK / 16; ++f) {
        const float* src = gwin + (size_t)(tb + 16 * f + prow) * LIF_D + pcol;
        __builtin_amdgcn_global_load_lds(
            (glb_uint*)(const void*)src,
            (lds_uint*)(void*)(slotbase + (size_t)f * 256), 16, 0, 0);
    }
}

__global__ __launch_bounds__(256, 1) void lif_v16_kernel(
    const float* __restrict__ current,
    const float* __restrict__ membrane,
    float* __restrict__ spikes,
    float* __restrict__ mem_out)
{
    #pragma clang fp contract(off)

    __shared__ __align__(16) float in_ring[2][CHUNK][CPB];   // 32 KB
    __shared__ unsigned mask_lds[2][8][CPB];                 // 1 KB spike bits

    const int wid  = threadIdx.x >> 6;   // 0=consumer 1=producer 2,3=writers
    const int lane = threadIdx.x & 63;
    const int blk  = blockIdx.x;         // 0..511
    const int bb   = blk >> 6;           // batch (1024/16 = 64 ch-blocks)
    const int ch0  = (blk & 63) * CPB;

    const float* gwin  = current + (size_t)bb * LIF_S * LIF_D + ch0;
    float*       sbase = spikes  + (size_t)bb * LIF_S * LIF_D + ch0;

    const int prow = lane >> 2;          // producer 16-row mapping
    const int pcol = (lane & 3) * 4;
    const int lx   = lane & 15;          // consumer channel (4-way broadcast)

    float mem = 0.0f;

    // ---- prologue: producer stages chunk 0; consumer loads membrane ----
    if (wid == 1) {
        stage_chunk16(gwin, 0, prow, pcol, &in_ring[0][0][0]);
        asm volatile("s_waitcnt vmcnt(0)" ::: "memory");
    } else if (wid == 0 && lane < CPB) {
        mem = membrane[bb * LIF_D + ch0 + lane];
    }
    __builtin_amdgcn_s_barrier();
    asm volatile("" ::: "memory");

    for (int h = 0; h < NH; ++h) {
        if (wid == 0) {
            // ---- consumer: v10's exact inner loop (broadcast reads) ----
            const float* ib = &in_ring[h & 1][0][lx];
            unsigned m[8];
            #pragma unroll
            for (int j = 0; j < 8; ++j) m[j] = 0u;

            float A[16], Bv[16];
            #pragma unroll
            for (int j = 0; j < 16; ++j) A[j]  = ib[j * CPB];
            #pragma unroll
            for (int j = 0; j < 16; ++j) Bv[j] = ib[(16 + j) * CPB];

            #pragma unroll
            for (int b = 0; b < 16; ++b) {
                const int wd = b >> 1;          // mask word (static)
                const int sh = (b & 1) * 16;    // bit base (static)
                #pragma unroll
                for (int j = 0; j < 16; ++j) {
                    const float c = ((b & 1) == 0) ? A[j] : Bv[j];  // static
                    const float v = 0.9f * mem + c;   // mul-then-add
                    const float w = v - 1.0f;         // off chain
                    const bool  f = (v >= 1.0f);
                    m[wd] |= f ? (1u << (sh + j)) : 0u;
                    mem = f ? w : v;                  // soft reset
                }
                if (b + 2 < 16) {                     // prefetch batch b+2
                    #pragma unroll
                    for (int j = 0; j < 16; ++j) {
                        if ((b & 1) == 0) A[j]  = ib[((b + 2) * 16 + j) * CPB];
                        else              Bv[j] = ib[((b + 2) * 16 + j) * CPB];
                    }
                }
            }

            if (lane < CPB) {
                #pragma unroll
                for (int j = 0; j < 8; ++j)
                    mask_lds[h & 1][j][lane] = m[j];
            }
            asm volatile("s_waitcnt lgkmcnt(0)" ::: "memory");
        } else if (wid == 1) {
            // ---- producer: stage chunk h+1 into the other slot ----
            if (h + 1 < NH) {
                stage_chunk16(gwin, (h + 1) * CHUNK, prow, pcol,
                              &in_ring[(h + 1) & 1][0][0]);
                asm volatile("s_waitcnt vmcnt(0)" ::: "memory");
            }
        } else {
            // ---- writers: expand masks of phase h-1 -> float4 stores ----
            if (h >= 1) {
                const int ph = (h - 1) & 1;
                const int tb = (h - 1) * CHUNK;
                const int rgrp = lane >> 2;           // 0..15 row sub
                const int c4   = lane & 3;            // float4 col group
                const int rbase = (wid == 3) ? 128 : 0;
                #pragma unroll
                for (int k = 0; k < 8; ++k) {
                    const int row = rbase + k * 16 + rgrp;      // local row
                    const int wIdx = row >> 5;
                    const int bit  = row & 31;
                    float4 vv;
                    vv.x = (float)((mask_lds[ph][wIdx][4 * c4 + 0] >> bit) & 1u);
                    vv.y = (float)((mask_lds[ph][wIdx][4 * c4 + 1] >> bit) & 1u);
                    vv.z = (float)((mask_lds[ph][wIdx][4 * c4 + 2] >> bit) & 1u);
                    vv.w = (float)((mask_lds[ph][wIdx][4 * c4 + 3] >> bit) & 1u);
                    *(float4*)(sbase + (size_t)(tb + row) * LIF_D + 4 * c4) = vv;
                }
                asm volatile("s_waitcnt lgkmcnt(0)" ::: "memory");
            }
        }
        __builtin_amdgcn_s_barrier();
        asm volatile("" ::: "memory");
    }

    // ---- epilogue: flush masks of phase NH-1; store final membrane ----
    if (wid >= 2) {
        const int ph = (NH - 1) & 1;
        const int tb = (NH - 1) * CHUNK;
        const int rgrp = lane >> 2;
        const int c4   = lane & 3;
        const int rbase = (wid == 3) ? 128 : 0;
        #pragma unroll
        for (int k = 0; k < 8; ++k) {
            const int row = rbase + k * 16 + rgrp;
            const int wIdx = row >> 5;
            const int bit  = row & 31;
            float4 vv;
            vv.x = (float)((mask_lds[ph][wIdx][4 * c4 + 0] >> bit) & 1u);
            vv.y = (float)((mask_lds[ph][wIdx][4 * c4 + 1] >> bit) & 1u);
            vv.z = (float)((mask_lds[ph][wIdx][4 * c4 + 2] >> bit) & 1u);
            vv.w = (float)((mask_lds[ph][wIdx][4 * c4 + 3] >> bit) & 1u);
            *(float4*)(sbase + (size_t)(tb + row) * LIF_D + 4 * c4) = vv;
        }
    } else if (wid == 0 && lane < CPB) {
        mem_out[bb * LIF_D + ch0 + lane] = mem;
    }
}

extern "C" void kernel_launch(void* const* d_in, const int* in_sizes, int n_in,
                              void* d_out, int out_size, void* d_ws, size_t ws_size,
                              hipStream_t stream) {
    const float* current  = (const float*)d_in[0];   // [8, 4096, 1024]
    const float* membrane = (const float*)d_in[1];   // [8, 1024]

    float* spikes  = (float*)d_out;                                 // [8,4096,1024]
    float* mem_out = (float*)d_out + (size_t)LIF_B * LIF_S * LIF_D; // [8,1024]

    dim3 block(256);                   // w0 consumer, w1 producer, w2-3 writers
    dim3 grid(LIF_B * LIF_D / CPB);    // 512 blocks (16 channels each, 2/CU)

    hipLaunchKernelGGL(lif_v16_kernel, grid, block, 0, stream,
                       current, membrane, spikes, mem_out);
}

// Round 23
// 72.882 us; speedup vs baseline: 3.0738x; 1.7111x over previous
//
#include <hip/hip_runtime.h>

// LIF neuron forward, v11 (RESTORED — best measured: 73.6us, r17).
// V = leak*V + I; spike = (V >= 1); V -= spike.
// current: [B=8, S=4096, D=1024] f32, membrane: [B, D] f32.
// Outputs concatenated: spikes [B,S,D] then mem_final [B,D], all f32.
//
// Final state of the search (r5-r22): consumer cadence 43-44 cyc/step is
// invariant across 12 structural variants; dur = 4096 x cadence = 73us.
// TLP attacks (same-block waves, independent blocks/CU) refuted; asm
// variants hit VALU->SGPR hazards; fat-register variants spill. This
// kernel: w0 consumer (asm chain, vcc-only, wave-mask -> writelane),
// w1 producer (1KB global_load_lds, distance-1), w2/w3 writers (mask ->
// float expand). 256 blocks x CPB=32, CHUNK=256, NH=16, raw barriers.
//
// Numerics (validated r5-r22, absmax 7.6e-6): forward spike == hard
// threshold exactly in fp32; mul-then-add (0x3f666666 = 0.9f), cmp>=1.0,
// mem = f ? v-1 : v. Bit-exact vs numpy fp32 replay.

#define LIF_B 8
#define LIF_S 4096
#define LIF_D 1024
#define CHUNK 256
#define NH    (LIF_S / CHUNK)   // 16
#define CPB   32                // channels per block

typedef __attribute__((address_space(3))) unsigned int lds_uint;
typedef const __attribute__((address_space(1))) unsigned int glb_uint;

// stage one 32KB chunk (256 rows x 32 ch) with 32 x 1KB global_load_lds.
// lane L -> row (L>>3), float col (L&7)*4; LDS dest linear (m173 pattern).
__device__ __forceinline__ void stage_chunk32(const float* gwin, int tb,
                                              int prow, int pcol,
                                              float* slotbase) {
    #pragma unroll
    for (int f = 0; f < CHUNK / 8; ++f) {
        const float* src = gwin + (size_t)(tb + 8 * f + prow) * LIF_D + pcol;
        __builtin_amdgcn_global_load_lds(
            (glb_uint*)(const void*)src,
            (lds_uint*)(void*)(slotbase + (size_t)f * 256), 16, 0, 0);
    }
}

// One LIF step: chain in asm; wave spike-mask lands in an SGPR pair; its
// low word (lanes 0-31 = this block's 32 channels) is banked into lane LB
// of vml via v_writelane (immediate lane select).
template<int LB>
__device__ __forceinline__ void lif_step(float c, float& mem, unsigned& vml) {
    float v_, w_;
    unsigned long long mk_;
    asm volatile(
        "v_mul_f32 %1, 0x3f666666, %3\n\t"   // v = 0.9f * mem (mul first)
        "v_add_f32 %1, %1, %4\n\t"           // v += c
        "v_add_f32 %2, -1.0, %1\n\t"         // w = v - 1  (off critical path)
        "v_cmp_ge_f32 %0, %1, 1.0\n\t"       // wave mask -> SGPR pair
        "v_cndmask_b32 %3, %1, %2, %0"       // mem = f ? w : v
        : "=&s"(mk_), "=&v"(v_), "=&v"(w_), "+v"(mem)
        : "v"(c));
    asm volatile("v_writelane_b32 %0, %1, %2"
                 : "+v"(vml)
                 : "s"((unsigned)mk_), "n"(LB));
}

#define LIF_B16_A()  do { \
    lif_step< 0>(A[ 0], mem, vml); lif_step< 1>(A[ 1], mem, vml); \
    lif_step< 2>(A[ 2], mem, vml); lif_step< 3>(A[ 3], mem, vml); \
    lif_step< 4>(A[ 4], mem, vml); lif_step< 5>(A[ 5], mem, vml); \
    lif_step< 6>(A[ 6], mem, vml); lif_step< 7>(A[ 7], mem, vml); \
    lif_step< 8>(A[ 8], mem, vml); lif_step< 9>(A[ 9], mem, vml); \
    lif_step<10>(A[10], mem, vml); lif_step<11>(A[11], mem, vml); \
    lif_step<12>(A[12], mem, vml); lif_step<13>(A[13], mem, vml); \
    lif_step<14>(A[14], mem, vml); lif_step<15>(A[15], mem, vml); } while (0)

#define LIF_B16_B()  do { \
    lif_step<16>(Bv[ 0], mem, vml); lif_step<17>(Bv[ 1], mem, vml); \
    lif_step<18>(Bv[ 2], mem, vml); lif_step<19>(Bv[ 3], mem, vml); \
    lif_step<20>(Bv[ 4], mem, vml); lif_step<21>(Bv[ 5], mem, vml); \
    lif_step<22>(Bv[ 6], mem, vml); lif_step<23>(Bv[ 7], mem, vml); \
    lif_step<24>(Bv[ 8], mem, vml); lif_step<25>(Bv[ 9], mem, vml); \
    lif_step<26>(Bv[10], mem, vml); lif_step<27>(Bv[11], mem, vml); \
    lif_step<28>(Bv[12], mem, vml); lif_step<29>(Bv[13], mem, vml); \
    lif_step<30>(Bv[14], mem, vml); lif_step<31>(Bv[15], mem, vml); } while (0)

__global__ __launch_bounds__(256, 1) void lif_v11_kernel(
    const float* __restrict__ current,
    const float* __restrict__ membrane,
    float* __restrict__ spikes,
    float* __restrict__ mem_out)
{
    #pragma clang fp contract(off)

    __shared__ __align__(16) float in_ring[2][CHUNK][CPB];   // 64 KB
    __shared__ unsigned mask_lds[2][8][64];                  // 4 KB step masks

    const int wid  = threadIdx.x >> 6;   // 0=consumer 1=producer 2,3=writers
    const int lane = threadIdx.x & 63;
    const int blk  = blockIdx.x;         // 0..255
    const int bb   = blk >> 5;           // batch (1024/32 = 32 ch-blocks)
    const int ch0  = (blk & 31) * CPB;

    const float* gwin  = current + (size_t)bb * LIF_S * LIF_D + ch0;
    float*       sbase = spikes  + (size_t)bb * LIF_S * LIF_D + ch0;

    const int prow = lane >> 3;          // producer 8-row mapping
    const int pcol = (lane & 7) * 4;

    float mem = 0.0f;

    // ---- prologue: producer stages chunk 0; consumer loads membrane ----
    if (wid == 1) {
        stage_chunk32(gwin, 0, prow, pcol, &in_ring[0][0][0]);
        asm volatile("s_waitcnt vmcnt(0)" ::: "memory");
    } else if (wid == 0 && lane < CPB) {
        mem = membrane[bb * LIF_D + ch0 + lane];
    }
    __builtin_amdgcn_s_barrier();
    asm volatile("" ::: "memory");

    for (int h = 0; h < NH; ++h) {
        if (wid == 0) {
            // ---- consumer: 256 steps = 8 groups of 32, asm chain ----
            const float* ib = &in_ring[h & 1][0][lane & 31];
            float A[16], Bv[16];
            #pragma unroll
            for (int j = 0; j < 16; ++j) A[j]  = ib[j * CPB];
            #pragma unroll
            for (int j = 0; j < 16; ++j) Bv[j] = ib[(16 + j) * CPB];
            unsigned vml = 0;

            #pragma unroll
            for (int g = 0; g < 8; ++g) {
                LIF_B16_A();
                if (g < 7) {
                    #pragma unroll
                    for (int j = 0; j < 16; ++j)
                        A[j] = ib[((2 * g + 2) * 16 + j) * CPB];
                }
                LIF_B16_B();
                mask_lds[h & 1][g][lane] = vml;   // step-masks of group g
                if (g < 7) {
                    #pragma unroll
                    for (int j = 0; j < 16; ++j)
                        Bv[j] = ib[((2 * g + 3) * 16 + j) * CPB];
                }
            }
            asm volatile("s_waitcnt lgkmcnt(0)" ::: "memory");
        } else if (wid == 1) {
            // ---- producer: stage chunk h+1 into the other slot ----
            if (h + 1 < NH) {
                stage_chunk32(gwin, (h + 1) * CHUNK, prow, pcol,
                              &in_ring[(h + 1) & 1][0][0]);
                asm volatile("s_waitcnt vmcnt(0)" ::: "memory");
            }
        } else {
            // ---- writers: expand step-masks of phase h-1 -> floats ----
            if (h >= 1) {
                const int ph = (h - 1) & 1;
                const int tb = (h - 1) * CHUNK;
                const int rbase = (wid == 3) ? 128 : 0;
                const int sub = lane >> 5;      // 0/1: which of 2 rows
                const int chb = lane & 31;      // channel = bit index
                #pragma unroll 8
                for (int k = 0; k < 64; ++k) {
                    const int rt = rbase + 2 * k + sub;             // row
                    const unsigned m = mask_lds[ph][rt >> 5][rt & 31];
                    const float sv = (float)((m >> chb) & 1u);      // 0/1
                    sbase[(size_t)(tb + rt) * LIF_D + chb] = sv;
                }
                asm volatile("s_waitcnt lgkmcnt(0)" ::: "memory");
            }
        }
        __builtin_amdgcn_s_barrier();
        asm volatile("" ::: "memory");
    }

    // ---- epilogue: flush masks of phase NH-1; store final membrane ----
    if (wid >= 2) {
        const int ph = (NH - 1) & 1;
        const int tb = (NH - 1) * CHUNK;
        const int rbase = (wid == 3) ? 128 : 0;
        const int sub = lane >> 5;
        const int chb = lane & 31;
        #pragma unroll 8
        for (int k = 0; k < 64; ++k) {
            const int rt = rbase + 2 * k + sub;
            const unsigned m = mask_lds[ph][rt >> 5][rt & 31];
            const float sv = (float)((m >> chb) & 1u);
            sbase[(size_t)(tb + rt) * LIF_D + chb] = sv;
        }
    } else if (wid == 0 && lane < CPB) {
        mem_out[bb * LIF_D + ch0 + lane] = mem;
    }
}

extern "C" void kernel_launch(void* const* d_in, const int* in_sizes, int n_in,
                              void* d_out, int out_size, void* d_ws, size_t ws_size,
                              hipStream_t stream) {
    const float* current  = (const float*)d_in[0];   // [8, 4096, 1024]
    const float* membrane = (const float*)d_in[1];   // [8, 1024]

    float* spikes  = (float*)d_out;                                 // [8,4096,1024]
    float* mem_out = (float*)d_out + (size_t)LIF_B * LIF_S * LIF_D; // [8,1024]

    dim3 block(256);                   // w0 consumer, w1 producer, w2-3 writers
    dim3 grid(LIF_B * LIF_D / CPB);    // 256 blocks (32 channels each)

    hipLaunchKernelGGL(lif_v11_kernel, grid, block, 0, stream,
                       current, membrane, spikes, mem_out);
}